// Round 5
// baseline (78.714 us; speedup 1.0000x reference)
//
#include <hip/hip_runtime.h>
#include <math.h>

#define Bb 32
#define Tt 131072
#define Lc 4096
#define NCh (Tt / Lc)   // 32 chunks per row
#define TPB 256
#define PT (Lc / TPB)   // 16 elements per thread

// padded LDS index: +1 float per 16 -> inter-lane stride 17 (conflict-free)
#define PIDX(j) ((j) + ((j) >> 4))
#define XSP (Lc + 64 + ((Lc + 64) >> 4))

__device__ __forceinline__ float sigmoidf_(float v) { return 1.0f / (1.0f + expf(-v)); }
__device__ __forceinline__ float softplusf_(float z) {
  return (z > 0.0f) ? (z + log1pf(expf(-z))) : log1pf(expf(z));
}
__device__ __forceinline__ float dgainf_(float sa) {
  return fminf(1000.0f, 1.0f / (sqrtf(sa) + 1e-8f));
}
__device__ __forceinline__ float pow16f_(float r) {
  float r2 = r * r, r4 = r2 * r2, r8 = r4 * r4;
  return r8 * r8;
}

// Block-wide inclusive scan of affine maps s -> m*s + b (thread order = time order).
__device__ __forceinline__ void affine_block_scan(
    float m, float b, float& Mex, float& Bex, float& Mtot, float& Btot, float* smem) {
  const int lane = threadIdx.x & 63;
  const int wave = threadIdx.x >> 6;
  float mi = m, bi = b;
#pragma unroll
  for (int d = 1; d < 64; d <<= 1) {
    float mp = __shfl_up(mi, d);
    float bp = __shfl_up(bi, d);
    if (lane >= d) { bi = fmaf(mi, bp, bi); mi *= mp; }
  }
  __syncthreads();
  if (lane == 63) { smem[2 * wave] = mi; smem[2 * wave + 1] = bi; }
  __syncthreads();
  float Mw = 1.0f, Bw = 0.0f;
#pragma unroll
  for (int wv = 0; wv < 3; ++wv) {
    if (wv < wave) {
      float mw = smem[2 * wv], bw = smem[2 * wv + 1];
      Bw = fmaf(mw, Bw, bw);
      Mw = mw * Mw;
    }
  }
  float mep = __shfl_up(mi, 1);
  float bep = __shfl_up(bi, 1);
  float me = (lane == 0) ? 1.0f : mep;
  float be = (lane == 0) ? 0.0f : bep;
  Mex = me * Mw;
  Bex = fmaf(me, Bw, be);
  Mtot = mi * Mw;
  Btot = fmaf(mi, Bw, bi);
}

// K1: depthwise causal conv(64) on x^2, combine, softplus -> p ; EMA1 chunk carry-ends.
// Weights read from global (uniform/scalar path) - keeps them off the LDS pipe.
__global__ __launch_bounds__(TPB) void k1_power(
    const float* __restrict__ x, const float* __restrict__ conv_w,
    const float* __restrict__ combine_w, const float* __restrict__ combine_b,
    const float* __restrict__ la_att,
    float* __restrict__ p_out, float* __restrict__ ce1, float* __restrict__ p0s) {
  __shared__ float xs[2][XSP];
  __shared__ float ssm[8];
  const int b = blockIdx.x / NCh;
  const int ch = blockIdx.x % NCh;
  const int t0 = ch * Lc;
#pragma unroll 1
  for (int c = 0; c < 2; ++c) {
    const float* xr = x + (size_t)(b * 2 + c) * Tt;
    for (int i = threadIdx.x; i < (Lc + 64) / 4; i += TPB) {
      int g = t0 - 64 + 4 * i;   // raw lds[j] = x^2[t0-64+j]
      float4 v = make_float4(0.f, 0.f, 0.f, 0.f);
      if (g >= 0) v = *(const float4*)(xr + g);
      const int j = 4 * i;
      xs[c][PIDX(j + 0)] = v.x * v.x;
      xs[c][PIDX(j + 1)] = v.y * v.y;
      xs[c][PIDX(j + 2)] = v.z * v.z;
      xs[c][PIDX(j + 3)] = v.w * v.w;
    }
  }
  __syncthreads();
  const int pb = 17 * (int)threadIdx.x;  // padded base of raw tl0 = 16*tid
  const float cb = combine_b[0];
  float pacc[PT];
#pragma unroll
  for (int i = 0; i < PT; ++i) pacc[i] = cb;
#pragma unroll 1
  for (int c = 0; c < 2; ++c) {
    const float cwc = combine_w[c];
    const float* wc = conv_w + (c << 6);
    // filt[t] = sum_k w[k]*xsq[t-63+k] ; raw lds index = tl0 + i + k + 1
    float win[16];
#pragma unroll
    for (int i = 0; i < 16; ++i) win[i] = xs[c][pb + 1 + i + ((1 + i) >> 4)];
#pragma unroll 1
    for (int kk = 0; kk < 4; ++kk) {
      const int rb = pb + 17 * kk + 18;   // padded addr of raw (tl0 + 17 + 16*kk)
#pragma unroll
      for (int k2 = 0; k2 < 16; ++k2) {
        const int k = kk * 16 + k2;
        const float wk = wc[k] * cwc;   // uniform -> scalar load, off the LDS pipe
#pragma unroll
        for (int i = 0; i < PT; ++i) pacc[i] = fmaf(wk, win[(k2 + i) & 15], pacc[i]);
        if (k < 63) win[k2] = xs[c][rb + k2 + ((k2 + 1) >> 4)];
      }
    }
  }
  float pv[PT];
#pragma unroll
  for (int i = 0; i < PT; ++i) pv[i] = softplusf_(pacc[i]) + 1e-8f;
  float* prow = p_out + (size_t)b * Tt + t0 + (int)threadIdx.x * PT;
#pragma unroll
  for (int i = 0; i < PT; i += 4)
    *(float4*)(prow + i) = make_float4(pv[i], pv[i + 1], pv[i + 2], pv[i + 3]);
  if (ch == 0 && threadIdx.x == 0) p0s[b] = pv[0];   // EMA init state p[b,0]
  const float a1 = sigmoidf_(la_att[0]);
  const float r1 = 1.0f - a1;
  float e1 = 0.0f;
#pragma unroll
  for (int i = 0; i < PT; ++i) e1 = fmaf(a1, pv[i], r1 * e1);
  float Mex, Bex, Mt, Bt;
  affine_block_scan(pow16f_(r1), e1, Mex, Bex, Mt, Bt, ssm);
  if (threadIdx.x == TPB - 1) ce1[blockIdx.x] = Bt;
}

// K3: per-block closed-form carry-in (rL underflow-exact), EMA1, dgain, EMA2 carry-ends.
__global__ __launch_bounds__(TPB) void k3_scan2(
    const float* __restrict__ p_ws, const float* __restrict__ ce1,
    const float* __restrict__ p0s,
    const float* __restrict__ la_att, const float* __restrict__ la_rel,
    float* __restrict__ ce2) {
  __shared__ float ssm[8];
  __shared__ float cism;
  const int b = blockIdx.x / NCh;
  const int ch = blockIdx.x % NCh;
  const float a1 = sigmoidf_(la_att[0]); const float r1 = 1.0f - a1;
  const float a2 = sigmoidf_(la_rel[0]); const float r2 = 1.0f - a2;
  if (threadIdx.x < 64) {
    const int j = threadIdx.x;
    const float lr1 = (float)Lc * logf(r1);
    float cv = 0.0f;
    if (j < ch)       cv = expf(lr1 * (float)(ch - 1 - j)) * ce1[b * NCh + j];
    else if (j == ch) cv = expf(lr1 * (float)ch) * p0s[b];
#pragma unroll
    for (int d = 32; d > 0; d >>= 1) cv += __shfl_down(cv, d);
    if (j == 0) cism = cv;
  }
  const float* prow = p_ws + (size_t)b * Tt + ch * Lc + threadIdx.x * PT;
  float pv[PT];
#pragma unroll
  for (int i = 0; i < PT; i += 4) {
    float4 v = *(const float4*)(prow + i);
    pv[i] = v.x; pv[i + 1] = v.y; pv[i + 2] = v.z; pv[i + 3] = v.w;
  }
  float e1 = 0.0f;
#pragma unroll
  for (int i = 0; i < PT; ++i) e1 = fmaf(a1, pv[i], r1 * e1);
  float Mex, Bex, Mt, Bt;
  affine_block_scan(pow16f_(r1), e1, Mex, Bex, Mt, Bt, ssm);  // barriers publish cism
  float y = fmaf(Mex, cism, Bex);
  float e2 = 0.0f;
#pragma unroll
  for (int i = 0; i < PT; ++i) {
    y = fmaf(a1, pv[i], r1 * y);
    float dg = dgainf_(y);
    e2 = fmaf(a2, dg, r2 * e2);
  }
  affine_block_scan(pow16f_(r2), e2, Mex, Bex, Mt, Bt, ssm);
  if (threadIdx.x == TPB - 1) ce2[blockIdx.x] = Bt;
}

// K5: carry-ins (closed form), exact gain (in-place over p), stats partials.
__global__ __launch_bounds__(TPB) void k5_gain_stats(
    const float* __restrict__ x, float* __restrict__ pg,
    const float* __restrict__ ce1, const float* __restrict__ ce2,
    const float* __restrict__ p0s,
    const float* __restrict__ la_att, const float* __restrict__ la_rel,
    float* __restrict__ partials) {
  __shared__ float ssm[8];
  __shared__ float red[4][4];
  __shared__ float cism[2];
  const int b = blockIdx.x / NCh;
  const int ch = blockIdx.x % NCh;
  const float a1 = sigmoidf_(la_att[0]); const float r1 = 1.0f - a1;
  const float a2 = sigmoidf_(la_rel[0]); const float r2 = 1.0f - a2;
  if (threadIdx.x < 64) {
    const int j = threadIdx.x;
    const float lr1 = (float)Lc * logf(r1);
    const float lr2 = (float)Lc * logf(r2);
    float c1 = 0.0f, c2 = 0.0f;
    if (j < ch) {
      c1 = expf(lr1 * (float)(ch - 1 - j)) * ce1[b * NCh + j];
      c2 = expf(lr2 * (float)(ch - 1 - j)) * ce2[b * NCh + j];
    } else if (j == ch) {
      const float p0 = p0s[b];
      c1 = expf(lr1 * (float)ch) * p0;
      c2 = expf(lr2 * (float)ch) * dgainf_(p0);
    }
#pragma unroll
    for (int d = 32; d > 0; d >>= 1) { c1 += __shfl_down(c1, d); c2 += __shfl_down(c2, d); }
    if (j == 0) { cism[0] = c1; cism[1] = c2; }
  }
  const size_t rowoff = (size_t)b * Tt + ch * Lc + threadIdx.x * PT;
  float pv[PT];
#pragma unroll
  for (int i = 0; i < PT; i += 4) {
    float4 v = *(const float4*)(pg + rowoff + i);
    pv[i] = v.x; pv[i + 1] = v.y; pv[i + 2] = v.z; pv[i + 3] = v.w;
  }
  float e1 = 0.0f;
#pragma unroll
  for (int i = 0; i < PT; ++i) e1 = fmaf(a1, pv[i], r1 * e1);
  float Mex, Bex, Mt, Bt;
  affine_block_scan(pow16f_(r1), e1, Mex, Bex, Mt, Bt, ssm);  // barriers publish cism
  float y = fmaf(Mex, cism[0], Bex);
  float dg[PT];
  float e2 = 0.0f;
#pragma unroll
  for (int i = 0; i < PT; ++i) {
    y = fmaf(a1, pv[i], r1 * y);
    dg[i] = dgainf_(y);
    e2 = fmaf(a2, dg[i], r2 * e2);
  }
  affine_block_scan(pow16f_(r2), e2, Mex, Bex, Mt, Bt, ssm);
  float g = fmaf(Mex, cism[1], Bex);
  float gv[PT];
#pragma unroll
  for (int i = 0; i < PT; ++i) { g = fmaf(a2, dg[i], r2 * g); gv[i] = g; }
#pragma unroll
  for (int i = 0; i < PT; i += 4)
    *(float4*)(pg + rowoff + i) = make_float4(gv[i], gv[i + 1], gv[i + 2], gv[i + 3]);
  const float* x0 = x + (size_t)(b * 2 + 0) * Tt + ch * Lc + threadIdx.x * PT;
  const float* x1 = x + (size_t)(b * 2 + 1) * Tt + ch * Lc + threadIdx.x * PT;
  float s0 = 0.f, q0 = 0.f, s1 = 0.f, q1 = 0.f;
#pragma unroll
  for (int i = 0; i < PT; i += 4) {
    float4 v0 = *(const float4*)(x0 + i);
    float4 v1 = *(const float4*)(x1 + i);
    float t;
    t = v0.x * gv[i];     s0 += t; q0 = fmaf(t, t, q0);
    t = v0.y * gv[i + 1]; s0 += t; q0 = fmaf(t, t, q0);
    t = v0.z * gv[i + 2]; s0 += t; q0 = fmaf(t, t, q0);
    t = v0.w * gv[i + 3]; s0 += t; q0 = fmaf(t, t, q0);
    t = v1.x * gv[i];     s1 += t; q1 = fmaf(t, t, q1);
    t = v1.y * gv[i + 1]; s1 += t; q1 = fmaf(t, t, q1);
    t = v1.z * gv[i + 2]; s1 += t; q1 = fmaf(t, t, q1);
    t = v1.w * gv[i + 3]; s1 += t; q1 = fmaf(t, t, q1);
  }
#pragma unroll
  for (int d = 32; d > 0; d >>= 1) {
    s0 += __shfl_down(s0, d); q0 += __shfl_down(q0, d);
    s1 += __shfl_down(s1, d); q1 += __shfl_down(q1, d);
  }
  const int lane = threadIdx.x & 63, wave = threadIdx.x >> 6;
  if (lane == 0) { red[wave][0] = s0; red[wave][1] = q0; red[wave][2] = s1; red[wave][3] = q1; }
  __syncthreads();
  if (threadIdx.x == 0) {
    float rs0 = 0, rq0 = 0, rs1 = 0, rq1 = 0;
#pragma unroll
    for (int wv = 0; wv < 4; ++wv) {
      rs0 += red[wv][0]; rq0 += red[wv][1]; rs1 += red[wv][2]; rq1 += red[wv][3];
    }
    float* pp = partials + (size_t)blockIdx.x * 4;
    pp[0] = rs0; pp[1] = rq0; pp[2] = rs1; pp[3] = rq1;
  }
}

// K7: per-block stats finalize (fold of old K6) + out = sA*x*g + off
__global__ __launch_bounds__(256) void k7_out(
    const float* __restrict__ x, const float* __restrict__ gain,
    const float* __restrict__ partials,
    const float* __restrict__ dc_w, const float* __restrict__ gamma,
    const float* __restrict__ beta, float* __restrict__ out) {
  __shared__ float stm[4];
  const int b = blockIdx.x >> 7;   // 128 blocks per batch row
  const int tid = threadIdx.x;
  float s0 = 0.f, q0 = 0.f, s1 = 0.f, q1 = 0.f;
  if (tid < NCh) {
    const float* pp = partials + (size_t)(b * NCh + tid) * 4;
    s0 = pp[0]; q0 = pp[1]; s1 = pp[2]; q1 = pp[3];
  }
#pragma unroll
  for (int d = 16; d > 0; d >>= 1) {
    s0 += __shfl_down(s0, d); q0 += __shfl_down(q0, d);
    s1 += __shfl_down(s1, d); q1 += __shfl_down(q1, d);
  }
  if (tid == 0) {
    const float m0 = s0 / (float)Tt, m1 = s1 / (float)Tt;
    const float v0 = q0 / (float)Tt - m0 * m0;
    const float v1 = q1 / (float)Tt - m1 * m1;
    const float dw0 = dc_w[0], dw1 = dc_w[1];
    const float sA0 = gamma[0] * dw0 / sqrtf(fmaf(dw0 * dw0, v0, 1e-5f));
    const float sA1 = gamma[1] * dw1 / sqrtf(fmaf(dw1 * dw1, v1, 1e-5f));
    stm[0] = sA0; stm[1] = beta[0] - sA0 * m0;
    stm[2] = sA1; stm[3] = beta[1] - sA1 * m1;
  }
  __syncthreads();
  const float sA0 = stm[0], off0 = stm[1], sA1 = stm[2], off1 = stm[3];
  const int t = (((blockIdx.x & 127) << 8) + tid) << 2;
  const float4 g = *(const float4*)(gain + (size_t)b * Tt + t);
  {
    const size_t o = (size_t)(b * 2 + 0) * Tt + t;
    const float4 xv = *(const float4*)(x + o);
    float4 ov;
    ov.x = fmaf(sA0 * g.x, xv.x, off0);
    ov.y = fmaf(sA0 * g.y, xv.y, off0);
    ov.z = fmaf(sA0 * g.z, xv.z, off0);
    ov.w = fmaf(sA0 * g.w, xv.w, off0);
    *(float4*)(out + o) = ov;
  }
  {
    const size_t o = (size_t)(b * 2 + 1) * Tt + t;
    const float4 xv = *(const float4*)(x + o);
    float4 ov;
    ov.x = fmaf(sA1 * g.x, xv.x, off1);
    ov.y = fmaf(sA1 * g.y, xv.y, off1);
    ov.z = fmaf(sA1 * g.z, xv.z, off1);
    ov.w = fmaf(sA1 * g.w, xv.w, off1);
    *(float4*)(out + o) = ov;
  }
}

extern "C" void kernel_launch(void* const* d_in, const int* in_sizes, int n_in,
                              void* d_out, int out_size, void* d_ws, size_t ws_size,
                              hipStream_t stream) {
  const float* x         = (const float*)d_in[0];
  const float* conv_w    = (const float*)d_in[1];
  const float* combine_w = (const float*)d_in[2];
  const float* combine_b = (const float*)d_in[3];
  const float* la_att    = (const float*)d_in[4];
  const float* la_rel    = (const float*)d_in[5];
  const float* dc_w      = (const float*)d_in[6];
  const float* dc_b      = (const float*)d_in[7];  (void)dc_b; // cancels in layernorm
  const float* gamma     = (const float*)d_in[8];
  const float* beta      = (const float*)d_in[9];
  float* out = (float*)d_out;
  float* ws = (float*)d_ws;

  float* pg       = ws;                              // B*T floats: p, overwritten by gain
  float* ce1      = ws + (size_t)Bb * Tt;            // B*NC
  float* ce2      = ce1 + Bb * NCh;                  // B*NC
  float* p0s      = ce2 + Bb * NCh;                  // B
  float* partials = p0s + Bb;                        // B*NC*4

  hipLaunchKernelGGL(k1_power, dim3(Bb * NCh), dim3(TPB), 0, stream,
                     x, conv_w, combine_w, combine_b, la_att, pg, ce1, p0s);
  hipLaunchKernelGGL(k3_scan2, dim3(Bb * NCh), dim3(TPB), 0, stream,
                     pg, ce1, p0s, la_att, la_rel, ce2);
  hipLaunchKernelGGL(k5_gain_stats, dim3(Bb * NCh), dim3(TPB), 0, stream,
                     x, pg, ce1, ce2, p0s, la_att, la_rel, partials);
  hipLaunchKernelGGL(k7_out, dim3(Bb * 128), dim3(256), 0, stream,
                     x, pg, partials, dc_w, gamma, beta, out);
}

// Round 6
// 66.107 us; speedup vs baseline: 1.1907x; 1.1907x over previous
//
#include <hip/hip_runtime.h>
#include <math.h>

#define Bb 32
#define Tt 131072
#define Lc 2048
#define NCh (Tt / Lc)   // 64 chunks per row
#define TPB1 128        // K1 block
#define PT1 16          // K1 elems/thread (Lc / TPB1)
#define TPBS 256        // K3/K5 block
#define PTS 8           // K3/K5 elems/thread (Lc / TPBS)

// padded LDS index: +1 float per 16 -> inter-lane stride 17 (conflict-free)
#define PIDX(j) ((j) + ((j) >> 4))
#define XSP (Lc + 64 + ((Lc + 64) >> 4) + 4)

__device__ __forceinline__ float sigmoidf_(float v) { return 1.0f / (1.0f + __expf(-v)); }
__device__ __forceinline__ float softplusf_(float z) {
  // max(z,0) + log(1+exp(-|z|)), fast intrinsics; abs err ~1e-6
  return fmaxf(z, 0.0f) + __logf(1.0f + __expf(-fabsf(z)));
}
__device__ __forceinline__ float dgainf_(float sa) {
  return fminf(1000.0f, __fdividef(1.0f, sqrtf(sa) + 1e-8f));
}
__device__ __forceinline__ float pow16f_(float r) {
  float r2 = r * r, r4 = r2 * r2, r8 = r4 * r4;
  return r8 * r8;
}
__device__ __forceinline__ float pow8f_(float r) {
  float r2 = r * r, r4 = r2 * r2;
  return r4 * r4;
}

// 4-wave block scan of affine maps s -> m*s + b (thread order = time order). TPB=256.
__device__ __forceinline__ void affine_block_scan(
    float m, float b, float& Mex, float& Bex, float& Mtot, float& Btot, float* smem) {
  const int lane = threadIdx.x & 63;
  const int wave = threadIdx.x >> 6;
  float mi = m, bi = b;
#pragma unroll
  for (int d = 1; d < 64; d <<= 1) {
    float mp = __shfl_up(mi, d);
    float bp = __shfl_up(bi, d);
    if (lane >= d) { bi = fmaf(mi, bp, bi); mi *= mp; }
  }
  __syncthreads();
  if (lane == 63) { smem[2 * wave] = mi; smem[2 * wave + 1] = bi; }
  __syncthreads();
  float Mw = 1.0f, Bw = 0.0f;
#pragma unroll
  for (int wv = 0; wv < 3; ++wv) {
    if (wv < wave) {
      float mw = smem[2 * wv], bw = smem[2 * wv + 1];
      Bw = fmaf(mw, Bw, bw);
      Mw = mw * Mw;
    }
  }
  float mep = __shfl_up(mi, 1);
  float bep = __shfl_up(bi, 1);
  float me = (lane == 0) ? 1.0f : mep;
  float be = (lane == 0) ? 0.0f : bep;
  Mex = me * Mw;
  Bex = fmaf(me, Bw, be);
  Mtot = mi * Mw;
  Btot = fmaf(mi, Bw, bi);
}

// K1: depthwise causal conv(64) on x^2, combine, softplus -> p ; EMA1 chunk carry-ends.
// Lc=2048, TPB=128, PT=16, single-channel LDS buffer (~9KB) -> 8 blocks/CU.
__global__ __launch_bounds__(TPB1, 4) void k1_power(
    const float* __restrict__ x, const float* __restrict__ conv_w,
    const float* __restrict__ combine_w, const float* __restrict__ combine_b,
    const float* __restrict__ la_att,
    float* __restrict__ p_out, float* __restrict__ ce1, float* __restrict__ p0s) {
  __shared__ float xs[XSP];
  __shared__ float ssm[2];
  const int b = blockIdx.x / NCh;
  const int ch = blockIdx.x % NCh;
  const int t0 = ch * Lc;
  const int pb = 17 * (int)threadIdx.x;  // padded base of raw tl0 = 16*tid
  const float cb = combine_b[0];
  float pacc[PT1];
#pragma unroll
  for (int i = 0; i < PT1; ++i) pacc[i] = cb;
#pragma unroll 1
  for (int c = 0; c < 2; ++c) {
    if (c) __syncthreads();   // all reads of previous channel done before overwrite
    const float* xr = x + (size_t)(b * 2 + c) * Tt;
    for (int i = threadIdx.x; i < (Lc + 64) / 4; i += TPB1) {
      int g = t0 - 64 + 4 * i;   // raw lds[j] = x^2[t0-64+j]
      float4 v = make_float4(0.f, 0.f, 0.f, 0.f);
      if (g >= 0) v = *(const float4*)(xr + g);
      const int j = 4 * i;
      xs[PIDX(j + 0)] = v.x * v.x;
      xs[PIDX(j + 1)] = v.y * v.y;
      xs[PIDX(j + 2)] = v.z * v.z;
      xs[PIDX(j + 3)] = v.w * v.w;
    }
    __syncthreads();
    const float cwc = combine_w[c];
    const float* wc = conv_w + (c << 6);
    // filt[t] = sum_k w[k]*xsq[t-63+k] ; raw lds index = tl0 + i + k + 1
    float win[16];
#pragma unroll
    for (int i = 0; i < 16; ++i) win[i] = xs[pb + 1 + i + ((1 + i) >> 4)];
#pragma unroll 1
    for (int kk = 0; kk < 4; ++kk) {
      const int rb = pb + 17 * kk + 18;   // padded addr of raw (tl0 + 17 + 16*kk)
#pragma unroll
      for (int k2 = 0; k2 < 16; ++k2) {
        const int k = kk * 16 + k2;
        const float wk = wc[k] * cwc;   // uniform -> scalar load
#pragma unroll
        for (int i = 0; i < PT1; ++i) pacc[i] = fmaf(wk, win[(k2 + i) & 15], pacc[i]);
        if (k < 63) win[k2] = xs[rb + k2 + ((k2 + 1) >> 4)];
      }
    }
  }
  float pv[PT1];
#pragma unroll
  for (int i = 0; i < PT1; ++i) pv[i] = softplusf_(pacc[i]) + 1e-8f;
  float* prow = p_out + (size_t)b * Tt + t0 + (int)threadIdx.x * PT1;
#pragma unroll
  for (int i = 0; i < PT1; i += 4)
    *(float4*)(prow + i) = make_float4(pv[i], pv[i + 1], pv[i + 2], pv[i + 3]);
  if (ch == 0 && threadIdx.x == 0) p0s[b] = pv[0];   // EMA init state p[b,0]
  const float a1 = sigmoidf_(la_att[0]);
  const float r1 = 1.0f - a1;
  float e1 = 0.0f;
#pragma unroll
  for (int i = 0; i < PT1; ++i) e1 = fmaf(a1, pv[i], r1 * e1);
  // 2-wave block composition: only the block-total is needed (ce1)
  float mi = pow16f_(r1), bi = e1;
  const int lane = threadIdx.x & 63;
#pragma unroll
  for (int d = 1; d < 64; d <<= 1) {
    float mp = __shfl_up(mi, d);
    float bp = __shfl_up(bi, d);
    if (lane >= d) { bi = fmaf(mi, bp, bi); mi *= mp; }
  }
  if (threadIdx.x == 63) { ssm[0] = mi; ssm[1] = bi; }
  __syncthreads();
  if (threadIdx.x == TPB1 - 1) ce1[blockIdx.x] = fmaf(mi, ssm[1], bi);
}

// K3: per-block closed-form carry-in (decay-exact), EMA1, dgain, EMA2 carry-ends.
__global__ __launch_bounds__(TPBS, 4) void k3_scan2(
    const float* __restrict__ p_ws, const float* __restrict__ ce1,
    const float* __restrict__ p0s,
    const float* __restrict__ la_att, const float* __restrict__ la_rel,
    float* __restrict__ ce2) {
  __shared__ float ssm[8];
  __shared__ float cism;
  const int b = blockIdx.x / NCh;
  const int ch = blockIdx.x % NCh;
  const float a1 = sigmoidf_(la_att[0]); const float r1 = 1.0f - a1;
  const float a2 = sigmoidf_(la_rel[0]); const float r2 = 1.0f - a2;
  if (threadIdx.x < 64) {
    const int j = threadIdx.x;
    const float lr1 = (float)Lc * __logf(r1);
    float cv = 0.0f;
    if (j < ch)       cv = __expf(lr1 * (float)(ch - 1 - j)) * ce1[b * NCh + j];
    else if (j == ch) cv = __expf(lr1 * (float)ch) * p0s[b];
#pragma unroll
    for (int d = 32; d > 0; d >>= 1) cv += __shfl_down(cv, d);
    if (j == 0) cism = cv;
  }
  const float* prow = p_ws + (size_t)b * Tt + ch * Lc + threadIdx.x * PTS;
  float pv[PTS];
#pragma unroll
  for (int i = 0; i < PTS; i += 4) {
    float4 v = *(const float4*)(prow + i);
    pv[i] = v.x; pv[i + 1] = v.y; pv[i + 2] = v.z; pv[i + 3] = v.w;
  }
  float e1 = 0.0f;
#pragma unroll
  for (int i = 0; i < PTS; ++i) e1 = fmaf(a1, pv[i], r1 * e1);
  float Mex, Bex, Mt, Bt;
  affine_block_scan(pow8f_(r1), e1, Mex, Bex, Mt, Bt, ssm);  // barriers publish cism
  float y = fmaf(Mex, cism, Bex);
  float e2 = 0.0f;
#pragma unroll
  for (int i = 0; i < PTS; ++i) {
    y = fmaf(a1, pv[i], r1 * y);
    float dg = dgainf_(y);
    e2 = fmaf(a2, dg, r2 * e2);
  }
  affine_block_scan(pow8f_(r2), e2, Mex, Bex, Mt, Bt, ssm);
  if (threadIdx.x == TPBS - 1) ce2[blockIdx.x] = Bt;
}

// K5: carry-ins (closed form), exact gain (in-place over p), stats partials.
__global__ __launch_bounds__(TPBS, 4) void k5_gain_stats(
    const float* __restrict__ x, float* __restrict__ pg,
    const float* __restrict__ ce1, const float* __restrict__ ce2,
    const float* __restrict__ p0s,
    const float* __restrict__ la_att, const float* __restrict__ la_rel,
    float* __restrict__ partials) {
  __shared__ float ssm[8];
  __shared__ float red[4][4];
  __shared__ float cism[2];
  const int b = blockIdx.x / NCh;
  const int ch = blockIdx.x % NCh;
  const float a1 = sigmoidf_(la_att[0]); const float r1 = 1.0f - a1;
  const float a2 = sigmoidf_(la_rel[0]); const float r2 = 1.0f - a2;
  if (threadIdx.x < 64) {
    const int j = threadIdx.x;
    const float lr1 = (float)Lc * __logf(r1);
    const float lr2 = (float)Lc * __logf(r2);
    float c1 = 0.0f, c2 = 0.0f;
    if (j < ch) {
      c1 = __expf(lr1 * (float)(ch - 1 - j)) * ce1[b * NCh + j];
      c2 = __expf(lr2 * (float)(ch - 1 - j)) * ce2[b * NCh + j];
    } else if (j == ch) {
      const float p0 = p0s[b];
      c1 = __expf(lr1 * (float)ch) * p0;
      c2 = __expf(lr2 * (float)ch) * dgainf_(p0);
    }
#pragma unroll
    for (int d = 32; d > 0; d >>= 1) { c1 += __shfl_down(c1, d); c2 += __shfl_down(c2, d); }
    if (j == 0) { cism[0] = c1; cism[1] = c2; }
  }
  const size_t rowoff = (size_t)b * Tt + ch * Lc + threadIdx.x * PTS;
  float pv[PTS];
#pragma unroll
  for (int i = 0; i < PTS; i += 4) {
    float4 v = *(const float4*)(pg + rowoff + i);
    pv[i] = v.x; pv[i + 1] = v.y; pv[i + 2] = v.z; pv[i + 3] = v.w;
  }
  float e1 = 0.0f;
#pragma unroll
  for (int i = 0; i < PTS; ++i) e1 = fmaf(a1, pv[i], r1 * e1);
  float Mex, Bex, Mt, Bt;
  affine_block_scan(pow8f_(r1), e1, Mex, Bex, Mt, Bt, ssm);  // barriers publish cism
  float y = fmaf(Mex, cism[0], Bex);
  float dg[PTS];
  float e2 = 0.0f;
#pragma unroll
  for (int i = 0; i < PTS; ++i) {
    y = fmaf(a1, pv[i], r1 * y);
    dg[i] = dgainf_(y);
    e2 = fmaf(a2, dg[i], r2 * e2);
  }
  affine_block_scan(pow8f_(r2), e2, Mex, Bex, Mt, Bt, ssm);
  float g = fmaf(Mex, cism[1], Bex);
  float gv[PTS];
#pragma unroll
  for (int i = 0; i < PTS; ++i) { g = fmaf(a2, dg[i], r2 * g); gv[i] = g; }
#pragma unroll
  for (int i = 0; i < PTS; i += 4)
    *(float4*)(pg + rowoff + i) = make_float4(gv[i], gv[i + 1], gv[i + 2], gv[i + 3]);
  const float* x0 = x + (size_t)(b * 2 + 0) * Tt + ch * Lc + threadIdx.x * PTS;
  const float* x1 = x + (size_t)(b * 2 + 1) * Tt + ch * Lc + threadIdx.x * PTS;
  float s0 = 0.f, q0 = 0.f, s1 = 0.f, q1 = 0.f;
#pragma unroll
  for (int i = 0; i < PTS; i += 4) {
    float4 v0 = *(const float4*)(x0 + i);
    float4 v1 = *(const float4*)(x1 + i);
    float t;
    t = v0.x * gv[i];     s0 += t; q0 = fmaf(t, t, q0);
    t = v0.y * gv[i + 1]; s0 += t; q0 = fmaf(t, t, q0);
    t = v0.z * gv[i + 2]; s0 += t; q0 = fmaf(t, t, q0);
    t = v0.w * gv[i + 3]; s0 += t; q0 = fmaf(t, t, q0);
    t = v1.x * gv[i];     s1 += t; q1 = fmaf(t, t, q1);
    t = v1.y * gv[i + 1]; s1 += t; q1 = fmaf(t, t, q1);
    t = v1.z * gv[i + 2]; s1 += t; q1 = fmaf(t, t, q1);
    t = v1.w * gv[i + 3]; s1 += t; q1 = fmaf(t, t, q1);
  }
#pragma unroll
  for (int d = 32; d > 0; d >>= 1) {
    s0 += __shfl_down(s0, d); q0 += __shfl_down(q0, d);
    s1 += __shfl_down(s1, d); q1 += __shfl_down(q1, d);
  }
  const int lane = threadIdx.x & 63, wave = threadIdx.x >> 6;
  if (lane == 0) { red[wave][0] = s0; red[wave][1] = q0; red[wave][2] = s1; red[wave][3] = q1; }
  __syncthreads();
  if (threadIdx.x == 0) {
    float rs0 = 0, rq0 = 0, rs1 = 0, rq1 = 0;
#pragma unroll
    for (int wv = 0; wv < 4; ++wv) {
      rs0 += red[wv][0]; rq0 += red[wv][1]; rs1 += red[wv][2]; rq1 += red[wv][3];
    }
    float* pp = partials + (size_t)blockIdx.x * 4;
    pp[0] = rs0; pp[1] = rq0; pp[2] = rs1; pp[3] = rq1;
  }
}

// K7: per-block stats finalize + out = sA*x*g + off
__global__ __launch_bounds__(256) void k7_out(
    const float* __restrict__ x, const float* __restrict__ gain,
    const float* __restrict__ partials,
    const float* __restrict__ dc_w, const float* __restrict__ gamma,
    const float* __restrict__ beta, float* __restrict__ out) {
  __shared__ float stm[4];
  const int b = blockIdx.x >> 7;   // 128 blocks per batch row
  const int tid = threadIdx.x;
  float s0 = 0.f, q0 = 0.f, s1 = 0.f, q1 = 0.f;
  if (tid < NCh) {   // NCh = 64
    const float* pp = partials + (size_t)(b * NCh + tid) * 4;
    s0 = pp[0]; q0 = pp[1]; s1 = pp[2]; q1 = pp[3];
  }
#pragma unroll
  for (int d = 32; d > 0; d >>= 1) {
    s0 += __shfl_down(s0, d); q0 += __shfl_down(q0, d);
    s1 += __shfl_down(s1, d); q1 += __shfl_down(q1, d);
  }
  if (tid == 0) {
    const float m0 = s0 / (float)Tt, m1 = s1 / (float)Tt;
    const float v0 = q0 / (float)Tt - m0 * m0;
    const float v1 = q1 / (float)Tt - m1 * m1;
    const float dw0 = dc_w[0], dw1 = dc_w[1];
    const float sA0 = gamma[0] * dw0 / sqrtf(fmaf(dw0 * dw0, v0, 1e-5f));
    const float sA1 = gamma[1] * dw1 / sqrtf(fmaf(dw1 * dw1, v1, 1e-5f));
    stm[0] = sA0; stm[1] = beta[0] - sA0 * m0;
    stm[2] = sA1; stm[3] = beta[1] - sA1 * m1;
  }
  __syncthreads();
  const float sA0 = stm[0], off0 = stm[1], sA1 = stm[2], off1 = stm[3];
  const int t = (((blockIdx.x & 127) << 8) + tid) << 2;
  const float4 g = *(const float4*)(gain + (size_t)b * Tt + t);
  {
    const size_t o = (size_t)(b * 2 + 0) * Tt + t;
    const float4 xv = *(const float4*)(x + o);
    float4 ov;
    ov.x = fmaf(sA0 * g.x, xv.x, off0);
    ov.y = fmaf(sA0 * g.y, xv.y, off0);
    ov.z = fmaf(sA0 * g.z, xv.z, off0);
    ov.w = fmaf(sA0 * g.w, xv.w, off0);
    *(float4*)(out + o) = ov;
  }
  {
    const size_t o = (size_t)(b * 2 + 1) * Tt + t;
    const float4 xv = *(const float4*)(x + o);
    float4 ov;
    ov.x = fmaf(sA1 * g.x, xv.x, off1);
    ov.y = fmaf(sA1 * g.y, xv.y, off1);
    ov.z = fmaf(sA1 * g.z, xv.z, off1);
    ov.w = fmaf(sA1 * g.w, xv.w, off1);
    *(float4*)(out + o) = ov;
  }
}

extern "C" void kernel_launch(void* const* d_in, const int* in_sizes, int n_in,
                              void* d_out, int out_size, void* d_ws, size_t ws_size,
                              hipStream_t stream) {
  const float* x         = (const float*)d_in[0];
  const float* conv_w    = (const float*)d_in[1];
  const float* combine_w = (const float*)d_in[2];
  const float* combine_b = (const float*)d_in[3];
  const float* la_att    = (const float*)d_in[4];
  const float* la_rel    = (const float*)d_in[5];
  const float* dc_w      = (const float*)d_in[6];
  const float* dc_b      = (const float*)d_in[7];  (void)dc_b; // cancels in layernorm
  const float* gamma     = (const float*)d_in[8];
  const float* beta      = (const float*)d_in[9];
  float* out = (float*)d_out;
  float* ws = (float*)d_ws;

  float* pg       = ws;                              // B*T floats: p, overwritten by gain
  float* ce1      = ws + (size_t)Bb * Tt;            // B*NCh
  float* ce2      = ce1 + Bb * NCh;                  // B*NCh
  float* p0s      = ce2 + Bb * NCh;                  // B
  float* partials = p0s + Bb;                        // B*NCh*4

  hipLaunchKernelGGL(k1_power, dim3(Bb * NCh), dim3(TPB1), 0, stream,
                     x, conv_w, combine_w, combine_b, la_att, pg, ce1, p0s);
  hipLaunchKernelGGL(k3_scan2, dim3(Bb * NCh), dim3(TPBS), 0, stream,
                     pg, ce1, p0s, la_att, la_rel, ce2);
  hipLaunchKernelGGL(k5_gain_stats, dim3(Bb * NCh), dim3(TPBS), 0, stream,
                     x, pg, ce1, ce2, p0s, la_att, la_rel, partials);
  hipLaunchKernelGGL(k7_out, dim3(Bb * 128), dim3(256), 0, stream,
                     x, pg, partials, dc_w, gamma, beta, out);
}